// Round 2
// baseline (3758.783 us; speedup 1.0000x reference)
//
#include <hip/hip_runtime.h>
#include <math.h>
#include <stdint.h>

#define NTOK 4096
#define DMODEL 512
#define NHEAD 8
#define DHEAD 64
#define CTXN 77
#define CTXD 768

typedef __attribute__((ext_vector_type(4))) float f4;

// async global->LDS, 16B per lane. LDS dest must be wave-uniform base; HW adds lane*16.
__device__ __forceinline__ void gload16(const float* g, float* l) {
  __builtin_amdgcn_global_load_lds(
      (const __attribute__((address_space(1))) unsigned int*)(uintptr_t)g,
      (__attribute__((address_space(3))) unsigned int*)(uintptr_t)l,
      16, 0, 0);
}

// ---------------------------------------------------------------- LayerNorm
__global__ __launch_bounds__(256) void ln512_kernel(const float* __restrict__ in,
    float* __restrict__ out, const float* __restrict__ g, const float* __restrict__ bta) {
  int row = blockIdx.x;
  const float* p = in + (size_t)row * DMODEL;
  int t = threadIdx.x;
  float a0 = p[t], a1 = p[t + 256];
  float s = a0 + a1;
#pragma unroll
  for (int o = 32; o; o >>= 1) s += __shfl_xor(s, o, 64);
  __shared__ float red[4];
  int w = t >> 6, lane = t & 63;
  if (lane == 0) red[w] = s;
  __syncthreads();
  s = red[0] + red[1] + red[2] + red[3];
  float mean = s * (1.0f / DMODEL);
  float d0 = a0 - mean, d1 = a1 - mean;
  float v = d0 * d0 + d1 * d1;
#pragma unroll
  for (int o = 32; o; o >>= 1) v += __shfl_xor(v, o, 64);
  __syncthreads();
  if (lane == 0) red[w] = v;
  __syncthreads();
  v = (red[0] + red[1] + red[2] + red[3]) * (1.0f / DMODEL);
  float rs = rsqrtf(v + 1e-5f);
  float* q = out + (size_t)row * DMODEL;
  q[t]       = d0 * rs * g[t]       + bta[t];
  q[t + 256] = d1 * rs * g[t + 256] + bta[t + 256];
}

// ---------------------------------------------------------------- generic GEMM (small/edge cases)
__global__ __launch_bounds__(256) void gemm_kernel(
    const float* __restrict__ A, int lda,
    const float* __restrict__ W, int ldw,
    float* __restrict__ C, int ldc,
    const float* __restrict__ bias,
    const float* __restrict__ resid, int ldr,
    int M, int K) {
  __shared__ __align__(16) float As[16][68];
  __shared__ __align__(16) float Ws[16][64];
  int tid = threadIdx.x;
  int tx = tid & 15, ty = tid >> 4;
  int m0 = blockIdx.y * 64, n0 = blockIdx.x * 64;
  int ak = tid & 15, am = tid >> 4;
  int wn = tid & 63, wk = tid >> 6;
  float acc[4][4] = {};
  for (int k0 = 0; k0 < K; k0 += 16) {
#pragma unroll
    for (int p = 0; p < 4; p++) {
      int m = am + p * 16;
      int gm = m0 + m;
      As[ak][m] = (gm < M) ? A[(size_t)gm * lda + k0 + ak] : 0.0f;
    }
#pragma unroll
    for (int p = 0; p < 4; p++) {
      int k = wk + p * 4;
      Ws[k][wn] = W[(size_t)(k0 + k) * ldw + n0 + wn];
    }
    __syncthreads();
#pragma unroll
    for (int kk = 0; kk < 16; kk++) {
      float a_[4], b_[4];
      *(float4*)a_ = *(const float4*)&As[kk][ty * 4];
      *(float4*)b_ = *(const float4*)&Ws[kk][tx * 4];
#pragma unroll
      for (int i = 0; i < 4; i++)
#pragma unroll
        for (int j = 0; j < 4; j++)
          acc[i][j] = fmaf(a_[i], b_[j], acc[i][j]);
    }
    __syncthreads();
  }
  int gn0 = n0 + tx * 4;
#pragma unroll
  for (int i = 0; i < 4; i++) {
    int gm = m0 + ty * 4 + i;
    if (gm >= M) continue;
    float o_[4];
#pragma unroll
    for (int j = 0; j < 4; j++) o_[j] = acc[i][j];
    if (bias) {
#pragma unroll
      for (int j = 0; j < 4; j++) o_[j] += bias[gn0 + j];
    }
    if (resid) {
      float r_[4];
      *(float4*)r_ = *(const float4*)&resid[(size_t)gm * ldr + gn0];
#pragma unroll
      for (int j = 0; j < 4; j++) o_[j] += r_[j];
    }
    *(float4*)&C[(size_t)gm * ldc + gn0] = *(float4*)o_;
  }
}

// ---------------------------------------------------------------- big GEMM: 128x64 tile, T3 2-phase
// Requires: M % 128 == 0, N % 64 == 0 (grid), K % 16 == 0, lda/ldw % 4 == 0.
// A staged row-major [128][16] via global_load_lds width-16 (2 insts/wave),
// W staged [16][64] (1 inst/wave). Double-buffered, one barrier per K-tile.
__global__ __launch_bounds__(256) void gemm128_kernel(
    const float* __restrict__ A, int lda,
    const float* __restrict__ W, int ldw,
    float* __restrict__ C, int ldc,
    const float* __restrict__ bias,
    const float* __restrict__ resid, int ldr,
    int K) {
  __shared__ __align__(16) float As[2][128][16];
  __shared__ __align__(16) float Ws[2][16][64];
  int tid = threadIdx.x;
  int wv = tid >> 6, ln = tid & 63;
  int m0 = blockIdx.y * 128, n0 = blockIdx.x * 64;
  // A staging: wave wv, chunk q in {0,1}: LDS rows wv*32+16q .. +15
  int arow0 = wv * 32 + (ln >> 2);
  int akc = (ln & 3) * 4;
  const float* aptr0 = A + (size_t)(m0 + arow0) * lda + akc;
  const float* aptr1 = aptr0 + (size_t)16 * lda;
  // W staging: wave wv covers k-rows wv*4 .. +3
  int wrow = wv * 4 + (ln >> 4);
  int wcol = (ln & 15) * 4;
  const float* wptr = W + (size_t)wrow * ldw + n0 + wcol;

  int tx = tid & 15, ty = tid >> 4;
  float acc[8][4] = {};

#define STAGE128(buf, kk0) do {                               \
    gload16(aptr0 + (kk0), &As[buf][wv * 32][0]);             \
    gload16(aptr1 + (kk0), &As[buf][wv * 32 + 16][0]);        \
    gload16(wptr + (size_t)(kk0) * ldw, &Ws[buf][wv * 4][0]); \
  } while (0)

  STAGE128(0, 0);
  __syncthreads();
  int cur = 0;
  for (int k0 = 0; k0 < K; k0 += 16) {
    if (k0 + 16 < K) STAGE128(cur ^ 1, k0 + 16);
#pragma unroll
    for (int k4 = 0; k4 < 4; k4++) {
      f4 a4[8];
#pragma unroll
      for (int i = 0; i < 8; i++)
        a4[i] = *(const f4*)&As[cur][ty + 16 * i][k4 * 4];
#pragma unroll
      for (int kk = 0; kk < 4; kk++) {
        f4 b = *(const f4*)&Ws[cur][k4 * 4 + kk][tx * 4];
#pragma unroll
        for (int i = 0; i < 8; i++) {
          acc[i][0] = fmaf(a4[i][kk], b[0], acc[i][0]);
          acc[i][1] = fmaf(a4[i][kk], b[1], acc[i][1]);
          acc[i][2] = fmaf(a4[i][kk], b[2], acc[i][2]);
          acc[i][3] = fmaf(a4[i][kk], b[3], acc[i][3]);
        }
      }
    }
    __syncthreads();
    cur ^= 1;
  }
#undef STAGE128

  int gn0 = n0 + tx * 4;
#pragma unroll
  for (int i = 0; i < 8; i++) {
    int gm = m0 + ty + 16 * i;
    float o_[4];
#pragma unroll
    for (int j = 0; j < 4; j++) o_[j] = acc[i][j];
    if (bias) {
#pragma unroll
      for (int j = 0; j < 4; j++) o_[j] += bias[gn0 + j];
    }
    if (resid) {
      float r_[4];
      *(float4*)r_ = *(const float4*)&resid[(size_t)gm * ldr + gn0];
#pragma unroll
      for (int j = 0; j < 4; j++) o_[j] += r_[j];
    }
    *(float4*)&C[(size_t)gm * ldc + gn0] = *(float4*)o_;
  }
}

// ---------------------------------------------------------------- self QK^T -> exp(s*scale) + row partial sums
// sim[bh,i,j] = exp(scale * dot64(q,k));  part[(bh*64+jb)*4096 + i] = sum_j(tile)
__global__ __launch_bounds__(256) void self_scores_exp_kernel(
    const float* __restrict__ q, const float* __restrict__ k, float* __restrict__ sim,
    float* __restrict__ part) {
  __shared__ __align__(16) float Qs[64][68];
  __shared__ __align__(16) float Ks[64][68];
  int bh = blockIdx.z;
  int b = bh >> 3, h = bh & 7;
  int i0 = blockIdx.y * 64, j0 = blockIdx.x * 64;
  int tid = threadIdx.x;
  int kd = tid & 63, r4 = tid >> 6;
  const float* qb = q + (size_t)b * NTOK * DMODEL + h * DHEAD;
  const float* kb = k + (size_t)b * NTOK * DMODEL + h * DHEAD;
#pragma unroll
  for (int p = 0; p < 16; p++) {
    int i = r4 + p * 4;
    Qs[kd][i] = qb[(size_t)(i0 + i) * DMODEL + kd];
    Ks[kd][i] = kb[(size_t)(j0 + i) * DMODEL + kd];
  }
  __syncthreads();
  int tx = tid & 15, ty = tid >> 4;
  float acc[4][4] = {};
#pragma unroll 8
  for (int kk = 0; kk < 64; kk++) {
    float a_[4], b_[4];
    *(float4*)a_ = *(const float4*)&Qs[kk][ty * 4];
    *(float4*)b_ = *(const float4*)&Ks[kk][tx * 4];
#pragma unroll
    for (int i = 0; i < 4; i++)
#pragma unroll
      for (int j = 0; j < 4; j++)
        acc[i][j] = fmaf(a_[i], b_[j], acc[i][j]);
  }
  // exp (scores ~ N(0,1), max ~4.5 -> no max-subtraction needed in fp32)
  float rsum[4];
#pragma unroll
  for (int i = 0; i < 4; i++) {
    float s = 0.0f;
#pragma unroll
    for (int j = 0; j < 4; j++) {
      float e = __expf(acc[i][j] * 0.125f);
      acc[i][j] = e;
      s += e;
    }
    rsum[i] = s;
  }
  // reduce partial sums across tx (16-lane groups share a row set)
#pragma unroll
  for (int i = 0; i < 4; i++) {
#pragma unroll
    for (int o = 8; o; o >>= 1) rsum[i] += __shfl_xor(rsum[i], o, 16);
  }
  float* ob = sim + (size_t)bh * NTOK * NTOK;
#pragma unroll
  for (int i = 0; i < 4; i++) {
    float o_[4];
#pragma unroll
    for (int j = 0; j < 4; j++) o_[j] = acc[i][j];
    *(float4*)&ob[(size_t)(i0 + ty * 4 + i) * NTOK + j0 + tx * 4] = *(float4*)o_;
  }
  if (tx == 0) {
    size_t pb = ((size_t)bh * 64 + blockIdx.x) * NTOK + i0 + ty * 4;
#pragma unroll
    for (int i = 0; i < 4; i++) part[pb + i] = rsum[i];
  }
}

// ---------------------------------------------------------------- P@V with in-place normalization
// Reads E=exp(s), reduces 64 partial sums/row -> 1/l, writes P=E/l back into sim (the output map),
// and accumulates out = P @ V.
__global__ __launch_bounds__(256) void attn_pv_norm_kernel(
    float* __restrict__ P, const float* __restrict__ V,
    const float* __restrict__ part, float* __restrict__ out) {
  __shared__ __align__(16) float Ps[64][68];
  __shared__ __align__(16) float Vs[64][64];
  __shared__ float lred[4][64];
  __shared__ float linv[64];
  int bh = blockIdx.z;
  int b = bh >> 3, h = bh & 7;
  int i0 = blockIdx.y * 64;
  float* Pb = P + (size_t)bh * NTOK * NTOK;
  const float* vb = V + (size_t)b * NTOK * DMODEL + h * DHEAD;
  int tid = threadIdx.x;
  int c = tid & 63, r4 = tid >> 6;
  int w = tid >> 6;
  // row sums: combine 64 j-block partials per row
  {
    float s = 0.0f;
    const float* pp = part + (size_t)bh * 64 * NTOK + i0 + c;
    for (int jb = w; jb < 64; jb += 4) s += pp[(size_t)jb * NTOK];
    lred[w][c] = s;
  }
  __syncthreads();
  if (tid < 64) linv[tid] = 1.0f / (lred[0][tid] + lred[1][tid] + lred[2][tid] + lred[3][tid]);
  __syncthreads();
  int tx = tid & 15, ty = tid >> 4;
  float acc[4][4] = {};
  for (int j0 = 0; j0 < NTOK; j0 += 64) {
#pragma unroll
    for (int p = 0; p < 16; p++) {
      int rr = r4 + p * 4;
      size_t off = (size_t)(i0 + rr) * NTOK + j0 + c;
      float pn = Pb[off] * linv[rr];
      Pb[off] = pn;               // final normalized attention map
      Ps[c][rr] = pn;
      Vs[rr][c] = vb[(size_t)(j0 + rr) * DMODEL + c];
    }
    __syncthreads();
#pragma unroll 8
    for (int kk = 0; kk < 64; kk++) {
      float a_[4], b_[4];
      *(float4*)a_ = *(const float4*)&Ps[kk][ty * 4];
      *(float4*)b_ = *(const float4*)&Vs[kk][tx * 4];
#pragma unroll
      for (int i = 0; i < 4; i++)
#pragma unroll
        for (int j = 0; j < 4; j++)
          acc[i][j] = fmaf(a_[i], b_[j], acc[i][j]);
    }
    __syncthreads();
  }
  float* ob = out + (size_t)b * NTOK * DMODEL + h * DHEAD;
#pragma unroll
  for (int i = 0; i < 4; i++) {
    float o_[4];
#pragma unroll
    for (int j = 0; j < 4; j++) o_[j] = acc[i][j];
    *(float4*)&ob[(size_t)(i0 + ty * 4 + i) * DMODEL + tx * 4] = *(float4*)o_;
  }
}

// ---------------------------------------------------------------- fused cross-attention
// block = 32 query rows (same b,h); K/V head-slice staged in LDS once per block.
__global__ __launch_bounds__(256) void cross_attn_kernel(
    const float* __restrict__ q, const float* __restrict__ k2,
    const float* __restrict__ v2, float* __restrict__ probs, float* __restrict__ out) {
  __shared__ float Ks[CTXN][64];
  __shared__ float Vs[CTXN][64];
  __shared__ float sp[4][80];
  int tid = threadIdx.x;
  int w = tid >> 6, lane = tid & 63;
  int r0 = blockIdx.x * 32;            // rows r0..r0+31, all same (b,h)
  int b = r0 >> 15;
  int h = (r0 >> 12) & 7;
  const float* kb = k2 + (size_t)b * CTXN * DMODEL + h * DHEAD;
  const float* vb = v2 + (size_t)b * CTXN * DMODEL + h * DHEAD;
  for (int idx = tid; idx < CTXN * 64; idx += 256) {
    int j = idx >> 6, d = idx & 63;
    Ks[j][d] = kb[(size_t)j * DMODEL + d];
    Vs[j][d] = vb[(size_t)j * DMODEL + d];
  }
  __syncthreads();
  for (int rr = w; rr < 32; rr += 4) {
    int r = r0 + rr;
    int i = r & (NTOK - 1);
    float qd = q[((size_t)b * NTOK + i) * DMODEL + h * DHEAD + lane];
    for (int j = 0; j < CTXN; j++) {
      float s = qd * Ks[j][lane];
#pragma unroll
      for (int o = 32; o; o >>= 1) s += __shfl_xor(s, o, 64);
      if (lane == 0) sp[w][j] = s * 0.125f;
    }
    float s0 = sp[w][lane];
    float s1 = (lane < 13) ? sp[w][64 + lane] : -3.4e38f;
    float m = fmaxf(s0, s1);
#pragma unroll
    for (int o = 32; o; o >>= 1) m = fmaxf(m, __shfl_xor(m, o, 64));
    float e0 = __expf(s0 - m);
    float e1 = (lane < 13) ? __expf(s1 - m) : 0.0f;
    float l = e0 + e1;
#pragma unroll
    for (int o = 32; o; o >>= 1) l += __shfl_xor(l, o, 64);
    float inv = 1.0f / l;
    float p0 = e0 * inv, p1 = e1 * inv;
    size_t rowbase = (size_t)r * CTXN;
    probs[rowbase + lane] = p0;
    if (lane < 13) probs[rowbase + 64 + lane] = p1;
    sp[w][lane] = p0;
    if (lane < 13) sp[w][64 + lane] = p1;
    float acc = 0.0f;
    for (int j = 0; j < CTXN; j++)
      acc = fmaf(sp[w][j], Vs[j][lane], acc);
    out[((size_t)b * NTOK + i) * DMODEL + h * DHEAD + lane] = acc;
  }
}

// ---------------------------------------------------------------- GEGLU (in-place: h[:, :2048] = hx * gelu(gate))
__global__ __launch_bounds__(256) void geglu_kernel(float* __restrict__ hbuf) {
  size_t idx = (size_t)blockIdx.x * 256 + threadIdx.x;   // 2*4096*2048 total
  size_t row = idx >> 11;
  int c = (int)(idx & 2047);
  float* base = hbuf + row * 4096;
  float hx = base[c];
  float g = base[2048 + c];
  float gl = 0.5f * g * (1.0f + erff(g * 0.70710678118654752f));
  base[c] = hx * gl;
}

// ---------------------------------------------------------------- launcher
extern "C" void kernel_launch(void* const* d_in, const int* in_sizes, int n_in,
                              void* d_out, int out_size, void* d_ws, size_t ws_size,
                              hipStream_t stream) {
  const float* x    = (const float*)d_in[0];
  const float* ctx  = (const float*)d_in[1];
  const float* ln1g = (const float*)d_in[2];
  const float* ln1b = (const float*)d_in[3];
  const float* ln2g = (const float*)d_in[4];
  const float* ln2b = (const float*)d_in[5];
  const float* ln3g = (const float*)d_in[6];
  const float* ln3b = (const float*)d_in[7];
  const float* wq1  = (const float*)d_in[8];
  const float* wk1  = (const float*)d_in[9];
  const float* wv1  = (const float*)d_in[10];
  const float* wo1  = (const float*)d_in[11];
  const float* bo1  = (const float*)d_in[12];
  const float* wq2  = (const float*)d_in[13];
  const float* wk2  = (const float*)d_in[14];
  const float* wv2  = (const float*)d_in[15];
  const float* wo2  = (const float*)d_in[16];
  const float* bo2  = (const float*)d_in[17];
  const float* ffw1 = (const float*)d_in[18];
  const float* ffb1 = (const float*)d_in[19];
  const float* ffw2 = (const float*)d_in[20];
  const float* ffb2 = (const float*)d_in[21];

  float* ws = (float*)d_ws;
  float* XN = ws +  0;          // 2*4096*512   (also reused as scores partial-sum buffer)
  float* Qb = ws +  4194304;
  float* Kb = ws +  8388608;
  float* Vb = ws + 12582912;
  float* AO = ws + 16777216;
  float* XB = ws + 20971520;
  float* HB = ws + 25165824;    // 2*4096*4096

  float* outx      = (float*)d_out;
  float* self_map  = outx + 4194304;     // 16*4096*4096
  float* cross_map = outx + 272629760;   // 16*4096*77

  const float* NUL = nullptr;

  // ---- self-attention ----
  ln512_kernel<<<dim3(8192), dim3(256), 0, stream>>>(x, XN, ln1g, ln1b);
  gemm128_kernel<<<dim3(8,64), dim3(256), 0, stream>>>(XN,512, wq1,512, Qb,512, NUL, NUL,0, 512);
  gemm128_kernel<<<dim3(8,64), dim3(256), 0, stream>>>(XN,512, wk1,512, Kb,512, NUL, NUL,0, 512);
  gemm128_kernel<<<dim3(8,64), dim3(256), 0, stream>>>(XN,512, wv1,512, Vb,512, NUL, NUL,0, 512);
  // XN is dead from here until ln2 writes it -> reuse as partial-sum scratch (16*64*4096 floats)
  self_scores_exp_kernel<<<dim3(64,64,16), dim3(256), 0, stream>>>(Qb, Kb, self_map, XN);
  attn_pv_norm_kernel<<<dim3(1,64,16), dim3(256), 0, stream>>>(self_map, Vb, XN, AO);
  gemm128_kernel<<<dim3(8,64), dim3(256), 0, stream>>>(AO,512, wo1,512, XB,512, bo1, x,512, 512);

  // ---- cross-attention ----
  ln512_kernel<<<dim3(8192), dim3(256), 0, stream>>>(XB, XN, ln2g, ln2b);
  gemm128_kernel<<<dim3(8,64), dim3(256), 0, stream>>>(XN,512, wq2,512, Qb,512, NUL, NUL,0, 512);
  gemm_kernel<<<dim3(8,3),   dim3(256), 0, stream>>>(ctx,768, wk2,512, Kb,512, NUL, NUL,0, 154,768);
  gemm_kernel<<<dim3(8,3),   dim3(256), 0, stream>>>(ctx,768, wv2,512, Vb,512, NUL, NUL,0, 154,768);
  cross_attn_kernel<<<dim3(2048), dim3(256), 0, stream>>>(Qb, Kb, Vb, cross_map, AO);
  gemm128_kernel<<<dim3(8,64), dim3(256), 0, stream>>>(AO,512, wo2,512, XB,512, bo2, XB,512, 512);

  // ---- GEGLU feed-forward ----
  ln512_kernel<<<dim3(8192), dim3(256), 0, stream>>>(XB, XN, ln3g, ln3b);
  gemm128_kernel<<<dim3(64,64), dim3(256), 0, stream>>>(XN,512, ffw1,4096, HB,4096, ffb1, NUL,0, 512);
  geglu_kernel<<<dim3(65536), dim3(256), 0, stream>>>(HB);
  gemm128_kernel<<<dim3(8,64), dim3(256), 0, stream>>>(HB,4096, ffw2,512, outx,512, ffb2, XB,512, 2048);
}